// Round 7
// baseline (257.973 us; speedup 1.0000x reference)
//
#include <hip/hip_runtime.h>

#define NB 64
#define NT 2048
#define NQD 512
#define NKD 512
#define NVD 512
#define NAD 256
#define NCH 16           // T-chunks per batch
#define CHT 128          // rows per chunk

typedef __attribute__((ext_vector_type(8))) short s16x8;
typedef __attribute__((ext_vector_type(4))) float fx4;
typedef __attribute__((ext_vector_type(4))) unsigned int u32x4;

__device__ __forceinline__ short f2bf(float x) {
  union { float f; unsigned u; } v; v.f = x;
  return (short)((v.u + 0x7fffu + ((v.u >> 16) & 1u)) >> 16);  // RNE
}

__device__ __forceinline__ unsigned cvt_pk_bf16(float lo, float hi) {
  unsigned r;
  asm("v_cvt_pk_bf16_f32 %0, %1, %2" : "=v"(r) : "v"(lo), "v"(hi));
  return r;
}

// tanh(x) = 1 - 2/(1+e^{2x});  exact saturation at +/-1, rel err ~1e-7
__device__ __forceinline__ float fast_tanh(float x) {
  float e = __expf(x + x);
  return 1.0f - 2.0f * __builtin_amdgcn_rcpf(e + 1.0f);
}

// convert 16 f32 (4x fx4) -> 32B bf16 granule, write as 2 swizzled 16B chunks
__device__ __forceinline__ void cvt_write32(short* lds, int lbase, int swz, const fx4* q) {
  u32x4 w0, w1;
  w0[0] = cvt_pk_bf16(q[0][0], q[0][1]); w0[1] = cvt_pk_bf16(q[0][2], q[0][3]);
  w0[2] = cvt_pk_bf16(q[1][0], q[1][1]); w0[3] = cvt_pk_bf16(q[1][2], q[1][3]);
  w1[0] = cvt_pk_bf16(q[2][0], q[2][1]); w1[1] = cvt_pk_bf16(q[2][2], q[2][3]);
  w1[2] = cvt_pk_bf16(q[3][0], q[3][1]); w1[3] = cvt_pk_bf16(q[3][2], q[3][3]);
  *(u32x4*)((char*)lds + ((lbase) ^ swz)) = w0;
  *(u32x4*)((char*)lds + ((lbase + 16) ^ swz)) = w1;
}

// ---- kernel 1: fused prep.
// blocks 0..63:  qpk[b][n] = query[b]·Wq[:,n] + bq[n] + bk[n]
// blocks 64..79: Bpk = Wk as bf16 packed in MFMA B-fragment lane order:
//   Bpk[(ks*1024 + wnt*64 + g*16 + h)*8 + j] = bf16(Wk[ks*32+g*8+j][wnt*16+h])
__global__ void prep_kernel(const float* __restrict__ query, const float* __restrict__ Wq,
                            const float* __restrict__ bq, const float* __restrict__ bk,
                            const float* __restrict__ Wk,
                            float* __restrict__ qpk, short* __restrict__ Bpk) {
  __shared__ float q[NQD];
  const int tid = threadIdx.x;
  if (blockIdx.x < NB) {
    const int b = blockIdx.x;
    for (int k = tid; k < NQD; k += 256) q[k] = query[b * NQD + k];
    __syncthreads();
    float acc = bq[tid] + bk[tid];
#pragma unroll 8
    for (int k = 0; k < NQD; ++k) acc += q[k] * Wq[k * NAD + tid];
    qpk[b * NAD + tid] = acc;
  } else {
    const int ks = blockIdx.x - NB;          // 0..15 (K-step)
#pragma unroll
    for (int rep = 0; rep < 4; ++rep) {
      const int o = rep * 256 + tid;         // chunk id within ks: 0..1023
      const int wnt = o >> 6;
      const int l = o & 63;
      const int g = l >> 4, h = l & 15;
      const int n = wnt * 16 + h;
      const int k0 = ks * 32 + g * 8;
      s16x8 v;
#pragma unroll
      for (int j = 0; j < 8; ++j) v[j] = f2bf(Wk[(size_t)(k0 + j) * NAD + n]);
      *(s16x8*)(Bpk + (size_t)(ks * 1024 + o) * 8) = v;
    }
  }
}

// ---- kernel 2: fused score+softmax_local+ctx_partial per (batch, 128-row chunk)
// Phase A: 2x 64-row MFMA sub-tiles (R6 core: BK=128 dbuf LDS, Bpk B-frags)
// Phase B: chunk-local softmax -> p=exp(s-m_loc), write raw p to attn out
// Phase C: ctx_loc = sum_t p[t]*value[t,:] (continuous streaming MAC)
__global__ void __launch_bounds__(256, 3)
fused_kernel(const float* __restrict__ key, const short* __restrict__ Bpk,
             const float* __restrict__ qpk, const float* __restrict__ Wo,
             const float* __restrict__ value,
             float* __restrict__ attn, float* __restrict__ stats,
             float* __restrict__ partial) {
  __shared__ short As[2][64 * 128];     // 2 x 16 KB
  __shared__ float sred[4][64];
  __shared__ float pp[CHT];             // scores, then p
  __shared__ float red2[4];
  __shared__ fx4 ctxred[128];
  const int tid = threadIdx.x;
  const int w = tid >> 6, l = tid & 63;
  const int g = l >> 4, h = l & 15;
  const int b = blockIdx.x >> 4, tc = blockIdx.x & (NCH - 1);
  const int trow0 = tc * CHT;

  const short* bbase = Bpk + (size_t)(w * 256 + l) * 8;
  const int r = tid >> 3, kseg = tid & 7;
  const int lbase0 = r * 256 + kseg * 32;
  const int lbase1 = lbase0 + 32 * 256;
  const int swz = (r & 7) << 4;
  const int rsw = (h & 7) << 4;

  // ---------- Phase A: score for 2 sub-tiles of 64 rows ----------
#pragma unroll 1
  for (int stile = 0; stile < 2; ++stile) {
    const int m0 = b * NT + trow0 + stile * 64;   // global row
    const float* asrc0 = key + (size_t)(m0 + r) * NKD + kseg * 16;
    const float* asrc1 = asrc0 + (size_t)32 * NKD;

    s16x8 bcur[4];
#pragma unroll
    for (int nt = 0; nt < 4; ++nt) bcur[nt] = *(const s16x8*)(bbase + nt * 512);

    {
      fx4 st[8];
#pragma unroll
      for (int i = 0; i < 4; ++i) st[i] = *(const fx4*)(asrc0 + i * 4);
#pragma unroll
      for (int i = 0; i < 4; ++i) st[4 + i] = *(const fx4*)(asrc1 + i * 4);
      cvt_write32(&As[0][0], lbase0, swz, &st[0]);
      cvt_write32(&As[0][0], lbase1, swz, &st[4]);
    }
    __syncthreads();

    fx4 acc[4][4];
#pragma unroll
    for (int i = 0; i < 4; ++i)
#pragma unroll
      for (int j = 0; j < 4; ++j) acc[i][j] = fx4{0.f, 0.f, 0.f, 0.f};

    int buf = 0;
    for (int c = 0; c < 4; ++c) {
      const bool notLast = (c < 3);
      fx4 st[8];
      if (notLast) {
        const float* gp0 = asrc0 + (c + 1) * 128;
        const float* gp1 = asrc1 + (c + 1) * 128;
#pragma unroll
        for (int i = 0; i < 4; ++i) st[i] = *(const fx4*)(gp0 + i * 4);
#pragma unroll
        for (int i = 0; i < 4; ++i) st[4 + i] = *(const fx4*)(gp1 + i * 4);
      }
#pragma unroll
      for (int kl = 0; kl < 4; ++kl) {
        const int ks = c * 4 + kl;
        s16x8 bnxt[4];
        if (ks < 15) {
#pragma unroll
          for (int nt = 0; nt < 4; ++nt)
            bnxt[nt] = *(const s16x8*)(bbase + (size_t)(ks + 1) * 8192 + nt * 512);
        }
        s16x8 af[4];
#pragma unroll
        for (int mt = 0; mt < 4; ++mt)
          af[mt] = *(const s16x8*)((const char*)&As[buf][0] +
                                   (((mt * 16 + h) * 256 + kl * 64 + g * 16) ^ rsw));
#pragma unroll
        for (int mt = 0; mt < 4; ++mt)
#pragma unroll
          for (int nt = 0; nt < 4; ++nt)
            acc[mt][nt] = __builtin_amdgcn_mfma_f32_16x16x32_bf16(af[mt], bcur[nt], acc[mt][nt], 0, 0, 0);
        if (ks < 15) {
#pragma unroll
          for (int nt = 0; nt < 4; ++nt) bcur[nt] = bnxt[nt];
        }
      }
      if (notLast) {
        cvt_write32(&As[buf ^ 1][0], lbase0, swz, &st[0]);
        cvt_write32(&As[buf ^ 1][0], lbase1, swz, &st[4]);
      }
      __syncthreads();
      buf ^= 1;
    }

    // epilogue: tanh + Wo reduce  (C layout col=h, row=4g+reg)
    float qv[4], wv[4];
#pragma unroll
    for (int nt = 0; nt < 4; ++nt) {
      const int n = w * 64 + nt * 16 + h;
      qv[nt] = qpk[b * NAD + n];
      wv[nt] = Wo[n];
    }
#pragma unroll
    for (int mt = 0; mt < 4; ++mt) {
#pragma unroll
      for (int rr = 0; rr < 4; ++rr) {
        float s = fast_tanh(acc[mt][0][rr] + qv[0]) * wv[0]
                + fast_tanh(acc[mt][1][rr] + qv[1]) * wv[1]
                + fast_tanh(acc[mt][2][rr] + qv[2]) * wv[2]
                + fast_tanh(acc[mt][3][rr] + qv[3]) * wv[3];
#pragma unroll
        for (int off = 1; off < 16; off <<= 1) s += __shfl_xor(s, off, 64);
        if (h == 0) sred[w][mt * 16 + g * 4 + rr] = s;
      }
    }
    __syncthreads();
    if (tid < 64)
      pp[stile * 64 + tid] = sred[0][tid] + sred[1][tid] + sred[2][tid] + sred[3][tid];
    __syncthreads();   // pp written; sred/As free for next sub-tile
  }

  // ---------- Phase B: chunk-local softmax over 128 scores ----------
  float m_loc, z_loc;
  {
    const float v = (tid < CHT) ? pp[tid] : -3.0e38f;
    float mm = v;
#pragma unroll
    for (int off = 1; off < 64; off <<= 1) mm = fmaxf(mm, __shfl_xor(mm, off, 64));
    if (l == 0) red2[w] = mm;
    __syncthreads();
    m_loc = fmaxf(fmaxf(red2[0], red2[1]), fmaxf(red2[2], red2[3]));
    const float p = (tid < CHT) ? __expf(v - m_loc) : 0.f;
    float ss = p;
#pragma unroll
    for (int off = 1; off < 64; off <<= 1) ss += __shfl_xor(ss, off, 64);
    __syncthreads();                    // red2 reuse
    if (l == 0) red2[w] = ss;
    __syncthreads();
    z_loc = red2[0] + red2[1] + red2[2] + red2[3];
    if (tid < CHT) {
      pp[tid] = p;                      // all pp reads above are done
      attn[(size_t)b * NT + trow0 + tid] = p;   // raw p; combine rescales
    }
    if (tid == 0) {
      stats[(b * NCH + tc) * 2] = m_loc;
      stats[(b * NCH + tc) * 2 + 1] = z_loc;
    }
    __syncthreads();
  }

  // ---------- Phase C: ctx_loc = sum_t p[t] * value[t,:] ----------
  {
    const int half = tid >> 7;          // even/odd rows
    const int vi = (tid & 127) * 4;
    const float* vp = value + ((size_t)(b * NT + trow0 + half)) * NVD + vi;
    fx4 s4 = fx4{0.f, 0.f, 0.f, 0.f};
#pragma unroll 8
    for (int t = 0; t < CHT; t += 2) {
      fx4 x = *(const fx4*)(vp + (size_t)t * NVD);
      s4 += x * pp[t + half];
    }
    if (half) ctxred[tid & 127] = s4;
    __syncthreads();
    if (!half) {
      s4 += ctxred[tid];
      *(fx4*)(partial + ((size_t)(b * NCH + tc)) * NVD + vi) = s4;
    }
  }
}

// ---- kernel 3: combine chunk partials -> ctx, rescale attn in place
__global__ void combine_kernel(const float* __restrict__ stats, const float* __restrict__ partial,
                               float* __restrict__ ctx, float* __restrict__ attn) {
  __shared__ float scl[NCH];
  const int b = blockIdx.x, tid = threadIdx.x;
  float m = -3.0e38f;
#pragma unroll
  for (int c = 0; c < NCH; ++c) m = fmaxf(m, stats[(b * NCH + c) * 2]);
  float Z = 0.f;
#pragma unroll
  for (int c = 0; c < NCH; ++c)
    Z += stats[(b * NCH + c) * 2 + 1] * __expf(stats[(b * NCH + c) * 2] - m);
  const float inv = 1.0f / Z;
  if (tid < NCH) scl[tid] = __expf(stats[(b * NCH + tid) * 2] - m);
  __syncthreads();
#pragma unroll
  for (int i = tid; i < NVD; i += 256) {
    float s = 0.f;
#pragma unroll
    for (int c = 0; c < NCH; ++c) s += partial[(size_t)(b * NCH + c) * NVD + i] * scl[c];
    ctx[b * NVD + i] = s * inv;
  }
#pragma unroll
  for (int j = tid; j < NT; j += 256) {
    attn[(size_t)b * NT + j] *= scl[j >> 7] * inv;
  }
}

extern "C" void kernel_launch(void* const* d_in, const int* in_sizes, int n_in,
                              void* d_out, int out_size, void* d_ws, size_t ws_size,
                              hipStream_t stream) {
  const float* query = (const float*)d_in[0];
  const float* key   = (const float*)d_in[1];
  const float* value = (const float*)d_in[2];
  const float* Wq    = (const float*)d_in[3];
  const float* bq    = (const float*)d_in[4];
  const float* Wk    = (const float*)d_in[5];
  const float* bk    = (const float*)d_in[6];
  const float* Wo    = (const float*)d_in[7];
  // d_in[8] = bo: unused — softmax over T is invariant to a uniform shift.

  float* out  = (float*)d_out;
  float* ctx  = out;                // [B][VD]
  float* attn = out + NB * NVD;     // [B][T]

  char* ws = (char*)d_ws;
  float* qpk     = (float*)(ws);                       // 64 KB
  short* Bpk     = (short*)(ws + 64 * 1024);           // 256 KB
  float* stats   = (float*)(ws + 320 * 1024);          // 8 KB (64x16x2)
  float* partial = (float*)(ws + 384 * 1024);          // 2 MB (64x16x512)

  prep_kernel<<<NB + 16, 256, 0, stream>>>(query, Wq, bq, bk, Wk, qpk, Bpk);
  fused_kernel<<<NB * NCH, 256, 0, stream>>>(key, Bpk, qpk, Wo, value, attn, stats, partial);
  combine_kernel<<<NB, 256, 0, stream>>>(stats, partial, ctx, attn);
}

// Round 8
// 171.122 us; speedup vs baseline: 1.5075x; 1.5075x over previous
//
#include <hip/hip_runtime.h>

#define NB 64
#define NT 2048
#define NQD 512
#define NKD 512
#define NVD 512
#define NAD 256

typedef __attribute__((ext_vector_type(8))) short s16x8;
typedef __attribute__((ext_vector_type(4))) float fx4;
typedef __attribute__((ext_vector_type(4))) unsigned int u32x4;

__device__ __forceinline__ short f2bf(float x) {
  union { float f; unsigned u; } v; v.f = x;
  return (short)((v.u + 0x7fffu + ((v.u >> 16) & 1u)) >> 16);  // RNE
}

__device__ __forceinline__ unsigned cvt_pk_bf16(float lo, float hi) {
  unsigned r;
  asm("v_cvt_pk_bf16_f32 %0, %1, %2" : "=v"(r) : "v"(lo), "v"(hi));
  return r;
}

// tanh(x) = 1 - 2/(1+e^{2x});  exact saturation at +/-1, rel err ~1e-7
__device__ __forceinline__ float fast_tanh(float x) {
  float e = __expf(x + x);
  return 1.0f - 2.0f * __builtin_amdgcn_rcpf(e + 1.0f);
}

// ---- kernel 1: fused prep.
// blocks 0..63:  qpk[b][n] = query[b]·Wq[:,n] + bq[n] + bk[n]
// blocks 64..79: Bpk = Wk as bf16 packed in MFMA B-fragment lane order:
//   Bpk[(ks*1024 + wnt*64 + g*16 + h)*8 + j] = bf16(Wk[ks*32+g*8+j][wnt*16+h])
//   so a wave's fragment load is one fully-coalesced 1KB request.
__global__ void prep_kernel(const float* __restrict__ query, const float* __restrict__ Wq,
                            const float* __restrict__ bq, const float* __restrict__ bk,
                            const float* __restrict__ Wk,
                            float* __restrict__ qpk, short* __restrict__ Bpk) {
  __shared__ float q[NQD];
  const int tid = threadIdx.x;
  if (blockIdx.x < NB) {
    const int b = blockIdx.x;
    for (int k = tid; k < NQD; k += 256) q[k] = query[b * NQD + k];
    __syncthreads();
    float acc = bq[tid] + bk[tid];
#pragma unroll 8
    for (int k = 0; k < NQD; ++k) acc += q[k] * Wq[k * NAD + tid];
    qpk[b * NAD + tid] = acc;
  } else {
    const int ks = blockIdx.x - NB;          // 0..15 (K-step)
#pragma unroll
    for (int rep = 0; rep < 4; ++rep) {
      const int o = rep * 256 + tid;         // chunk id within ks: 0..1023
      const int wnt = o >> 6;
      const int l = o & 63;
      const int g = l >> 4, h = l & 15;
      const int n = wnt * 16 + h;
      const int k0 = ks * 32 + g * 8;
      s16x8 v;
#pragma unroll
      for (int j = 0; j < 8; ++j) v[j] = f2bf(Wk[(size_t)(k0 + j) * NAD + n]);
      *(s16x8*)(Bpk + (size_t)(ks * 1024 + o) * 8) = v;
    }
  }
}

// ---- kernel 2: fused GEMM(key@Wk) + tanh + ·Wo reduce -> score[b*T+t]
// BM=64, FULL-K A-tile staged once into swizzled LDS (one barrier), then a
// barrier-free K-loop. B frags from Bpk (L2-resident, coalesced 1KB wave
// loads), reg-prefetched 2 K-steps deep. 16 MFMA / K-step / wave.
__global__ void __launch_bounds__(256, 2)
score_kernel(const float* __restrict__ key, const short* __restrict__ Bpk,
             const float* __restrict__ qpk, const float* __restrict__ Wo,
             float* __restrict__ score) {
  __shared__ short As[64 * 512];        // 64 KB: [row][k] bf16, byte^((row&7)<<4)
  __shared__ float sred[4][64];
  const int tid = threadIdx.x;
  const int w = tid >> 6, l = tid & 63;
  const int g = l >> 4, h = l & 15;
  const int m0 = blockIdx.x * 64;       // 32 blocks/batch; tiles never span batches
  const int b = m0 >> 11;

  // B fragment base: nt-panels 1KB apart, K-steps 8KB apart
  const short* bbase = Bpk + (size_t)(w * 256 + l) * 8;

  // 2-deep B prefetch: issue ks=0,1 before the staging burst
  s16x8 bcur[4], bn1[4];
#pragma unroll
  for (int nt = 0; nt < 4; ++nt) bcur[nt] = *(const s16x8*)(bbase + nt * 512);
#pragma unroll
  for (int nt = 0; nt < 4; ++nt) bn1[nt] = *(const s16x8*)(bbase + 8192 + nt * 512);

  // ---- stage full A tile: 64 rows x 512 k, f32 -> bf16, coalesced 8KB/iter
  {
    const float* tile = key + (size_t)m0 * NKD;
#pragma unroll
    for (int j = 0; j < 16; ++j) {
      const int c = tid + j * 256;      // 16B-bf16 granule id (0..4095)
      const float* gp = tile + c * 8;
      fx4 x0 = *(const fx4*)gp;
      fx4 x1 = *(const fx4*)(gp + 4);
      u32x4 pw;
      pw[0] = cvt_pk_bf16(x0[0], x0[1]);
      pw[1] = cvt_pk_bf16(x0[2], x0[3]);
      pw[2] = cvt_pk_bf16(x1[0], x1[1]);
      pw[3] = cvt_pk_bf16(x1[2], x1[3]);
      const int row = c >> 6, col = c & 63;
      *(u32x4*)((char*)As + ((row * 1024 + col * 16) ^ ((row & 7) << 4))) = pw;
    }
  }
  __syncthreads();

  fx4 acc[4][4];
#pragma unroll
  for (int i = 0; i < 4; ++i)
#pragma unroll
    for (int j = 0; j < 4; ++j) acc[i][j] = fx4{0.f, 0.f, 0.f, 0.f};

  int abase[4];
#pragma unroll
  for (int mt = 0; mt < 4; ++mt) abase[mt] = (mt * 16 + h) * 1024 + g * 16;
  const int sw = (h & 7) << 4;

  // ---- barrier-free K-loop, B prefetched 2 deep
#pragma unroll 2
  for (int ks = 0; ks < 16; ++ks) {
    s16x8 bn2[4];
    if (ks < 14) {
#pragma unroll
      for (int nt = 0; nt < 4; ++nt)
        bn2[nt] = *(const s16x8*)(bbase + (size_t)(ks + 2) * 8192 + nt * 512);
    }
    s16x8 af[4];
#pragma unroll
    for (int mt = 0; mt < 4; ++mt)
      af[mt] = *(const s16x8*)((const char*)As + ((abase[mt] + ks * 64) ^ sw));
#pragma unroll
    for (int mt = 0; mt < 4; ++mt)
#pragma unroll
      for (int nt = 0; nt < 4; ++nt)
        acc[mt][nt] = __builtin_amdgcn_mfma_f32_16x16x32_bf16(af[mt], bcur[nt], acc[mt][nt], 0, 0, 0);
#pragma unroll
    for (int nt = 0; nt < 4; ++nt) bcur[nt] = bn1[nt];
    if (ks < 14) {
#pragma unroll
      for (int nt = 0; nt < 4; ++nt) bn1[nt] = bn2[nt];
    }
  }

  // epilogue: score row m = m0 + mt*16 + 4g + reg  (C layout col=h, row=4g+reg)
  float qv[4], wv[4];
#pragma unroll
  for (int nt = 0; nt < 4; ++nt) {
    const int n = w * 64 + nt * 16 + h;
    qv[nt] = qpk[b * NAD + n];
    wv[nt] = Wo[n];
  }
#pragma unroll
  for (int mt = 0; mt < 4; ++mt) {
#pragma unroll
    for (int rr = 0; rr < 4; ++rr) {
      float s = fast_tanh(acc[mt][0][rr] + qv[0]) * wv[0]
              + fast_tanh(acc[mt][1][rr] + qv[1]) * wv[1]
              + fast_tanh(acc[mt][2][rr] + qv[2]) * wv[2]
              + fast_tanh(acc[mt][3][rr] + qv[3]) * wv[3];
#pragma unroll
      for (int off = 1; off < 16; off <<= 1) s += __shfl_xor(s, off, 64);
      if (h == 0) sred[w][mt * 16 + g * 4 + rr] = s;
    }
  }
  __syncthreads();
  if (tid < 64)
    score[m0 + tid] = sred[0][tid] + sred[1][tid] + sred[2][tid] + sred[3][tid];
}

// ---- kernel 3: softmax over T per batch (bo dropped: softmax shift-invariant)
__global__ void softmax_kernel(const float* __restrict__ score, float* __restrict__ attn) {
  __shared__ float redm[4];
  __shared__ float reds[4];
  const int b = blockIdx.x, tid = threadIdx.x;
  const float* s = score + (size_t)b * NT;
  float v[8];
  float m = -3.0e38f;
#pragma unroll
  for (int j = 0; j < 8; ++j) { v[j] = s[tid + j * 256]; m = fmaxf(m, v[j]); }
#pragma unroll
  for (int off = 1; off < 64; off <<= 1) m = fmaxf(m, __shfl_xor(m, off, 64));
  if ((tid & 63) == 0) redm[tid >> 6] = m;
  __syncthreads();
  m = fmaxf(fmaxf(redm[0], redm[1]), fmaxf(redm[2], redm[3]));
  float sum = 0.f;
#pragma unroll
  for (int j = 0; j < 8; ++j) { v[j] = __expf(v[j] - m); sum += v[j]; }
#pragma unroll
  for (int off = 1; off < 64; off <<= 1) sum += __shfl_xor(sum, off, 64);
  if ((tid & 63) == 0) reds[tid >> 6] = sum;
  __syncthreads();
  sum = reds[0] + reds[1] + reds[2] + reds[3];
  const float inv = 1.0f / sum;
#pragma unroll
  for (int j = 0; j < 8; ++j) attn[(size_t)b * NT + tid + j * 256] = v[j] * inv;
}

// ---- kernel 4: partial context over 64-row t-chunks (float4 loads)
__global__ void ctx_partial_kernel(const float* __restrict__ attn, const float* __restrict__ value,
                                   float* __restrict__ partial) {
  __shared__ float a[64];
  __shared__ fx4 red[128];
  const int blk = blockIdx.x;       // b*32 + tc
  const int b = blk >> 5, tc = blk & 31;
  const int tid = threadIdx.x;
  if (tid < 64) a[tid] = attn[(size_t)b * NT + tc * 64 + tid];
  __syncthreads();
  const int half = tid >> 7;        // 0: even rows, 1: odd rows
  const int vi = (tid & 127) * 4;   // 128 threads cover VD=512
  const float* vp = value + ((size_t)b * NT + tc * 64 + half) * NVD + vi;
  fx4 s = fx4{0.f, 0.f, 0.f, 0.f};
#pragma unroll 8
  for (int t = 0; t < 64; t += 2) {
    fx4 x = *(const fx4*)(vp + (size_t)t * NVD);
    const float wt = a[t + half];
    s += x * wt;
  }
  if (half) red[tid & 127] = s;
  __syncthreads();
  if (!half) {
    s += red[tid];
    *(fx4*)(partial + (size_t)blk * NVD + vi) = s;
  }
}

// ---- kernel 5: reduce partials -> context
__global__ void ctx_reduce_kernel(const float* __restrict__ partial, float* __restrict__ ctx) {
  const int i = blockIdx.x * 256 + threadIdx.x;  // < NB*NVD
  const int b = i >> 9, v = i & (NVD - 1);
  float s = 0.f;
#pragma unroll
  for (int tc = 0; tc < 32; ++tc) s += partial[(size_t)(b * 32 + tc) * NVD + v];
  ctx[i] = s;
}

extern "C" void kernel_launch(void* const* d_in, const int* in_sizes, int n_in,
                              void* d_out, int out_size, void* d_ws, size_t ws_size,
                              hipStream_t stream) {
  const float* query = (const float*)d_in[0];
  const float* key   = (const float*)d_in[1];
  const float* value = (const float*)d_in[2];
  const float* Wq    = (const float*)d_in[3];
  const float* bq    = (const float*)d_in[4];
  const float* Wk    = (const float*)d_in[5];
  const float* bk    = (const float*)d_in[6];
  const float* Wo    = (const float*)d_in[7];
  // d_in[8] = bo: unused — softmax over T is invariant to a uniform shift.

  float* out  = (float*)d_out;
  float* ctx  = out;                // [B][VD]
  float* attn = out + NB * NVD;     // [B][T]

  char* ws = (char*)d_ws;
  float* qpk     = (float*)(ws);                                   // 64 KB
  short* Bpk     = (short*)(ws + 64 * 1024);                       // 256 KB
  float* score   = (float*)(ws + (64 + 256) * 1024);               // 512 KB
  float* partial = (float*)(ws + (64 + 256 + 512) * 1024);         // 4 MB

  prep_kernel<<<NB + 16, 256, 0, stream>>>(query, Wq, bq, bk, Wk, qpk, Bpk);
  score_kernel<<<(NB * NT) / 64, 256, 0, stream>>>(key, Bpk, qpk, Wo, score);
  softmax_kernel<<<NB, 256, 0, stream>>>(score, attn);
  ctx_partial_kernel<<<NB * 32, 256, 0, stream>>>(attn, value, partial);
  ctx_reduce_kernel<<<(NB * NVD) / 256, 256, 0, stream>>>(partial, ctx);
}

// Round 9
// 156.502 us; speedup vs baseline: 1.6484x; 1.0934x over previous
//
#include <hip/hip_runtime.h>

#define NB 64
#define NT 2048
#define NQD 512
#define NKD 512
#define NVD 512
#define NAD 256

typedef __attribute__((ext_vector_type(8))) short s16x8;
typedef __attribute__((ext_vector_type(4))) float fx4;
typedef __attribute__((ext_vector_type(4))) unsigned int u32x4;

__device__ __forceinline__ short f2bf(float x) {
  union { float f; unsigned u; } v; v.f = x;
  return (short)((v.u + 0x7fffu + ((v.u >> 16) & 1u)) >> 16);  // RNE
}

__device__ __forceinline__ unsigned cvt_pk_bf16(float lo, float hi) {
  unsigned r;
  asm("v_cvt_pk_bf16_f32 %0, %1, %2" : "=v"(r) : "v"(lo), "v"(hi));
  return r;
}

// tanh(x) = 1 - 2/(1+e^{2x});  exact saturation at +/-1, rel err ~1e-7
__device__ __forceinline__ float fast_tanh(float x) {
  float e = __expf(x + x);
  return 1.0f - 2.0f * __builtin_amdgcn_rcpf(e + 1.0f);
}

__device__ __forceinline__ void gload_lds16(const void* g, void* l) {
  __builtin_amdgcn_global_load_lds(
      (const __attribute__((address_space(1))) unsigned int*)g,
      (__attribute__((address_space(3))) unsigned int*)l, 16, 0, 0);
}

// ---- kernel 1: fused prep.
// blocks 0..63:  qpk[b][n] = query[b]·Wq[:,n] + bq[n] + bk[n]
// blocks 64..79: Bpk = Wk as bf16 packed in MFMA B-fragment lane order:
//   Bpk[(ks*1024 + wnt*64 + g*16 + h)*8 + j] = bf16(Wk[ks*32+g*8+j][wnt*16+h])
__global__ void prep_kernel(const float* __restrict__ query, const float* __restrict__ Wq,
                            const float* __restrict__ bq, const float* __restrict__ bk,
                            const float* __restrict__ Wk,
                            float* __restrict__ qpk, short* __restrict__ Bpk) {
  __shared__ float q[NQD];
  const int tid = threadIdx.x;
  if (blockIdx.x < NB) {
    const int b = blockIdx.x;
    for (int k = tid; k < NQD; k += 256) q[k] = query[b * NQD + k];
    __syncthreads();
    float acc = bq[tid] + bk[tid];
#pragma unroll 8
    for (int k = 0; k < NQD; ++k) acc += q[k] * Wq[k * NAD + tid];
    qpk[b * NAD + tid] = acc;
  } else {
    const int ks = blockIdx.x - NB;          // 0..15 (K-step)
#pragma unroll
    for (int rep = 0; rep < 4; ++rep) {
      const int o = rep * 256 + tid;         // chunk id within ks: 0..1023
      const int wnt = o >> 6;
      const int l = o & 63;
      const int g = l >> 4, h = l & 15;
      const int n = wnt * 16 + h;
      const int k0 = ks * 32 + g * 8;
      s16x8 v;
#pragma unroll
      for (int j = 0; j < 8; ++j) v[j] = f2bf(Wk[(size_t)(k0 + j) * NAD + n]);
      *(s16x8*)(Bpk + (size_t)(ks * 1024 + o) * 8) = v;
    }
  }
}

// ---- kernel 2: fused GEMM(key@Wk) + tanh + ·Wo reduce -> score[b*T+t]
// BM=64, BK=64-f32 chunks (8), A staged via global_load_lds DMA (f32, no
// reg roundtrip) into 2x16KB dbuf. Source-address granule swizzle
// (c ^= row&15) with linear LDS dest => conflict-free swizzled ds_reads.
// f32->bf16 cvt at fragment-read time. B frags from Bpk (coalesced 1KB wave
// loads, L2-resident), reg-prefetched 2 K-steps deep.
__global__ void __launch_bounds__(256, 3)
score_kernel(const float* __restrict__ key, const short* __restrict__ Bpk,
             const float* __restrict__ qpk, const float* __restrict__ Wo,
             float* __restrict__ score) {
  __shared__ float As[2][64 * 64];      // 2 x 16 KB f32, granule-swizzled content
  __shared__ float sred[4][64];
  const int tid = threadIdx.x;
  const int w = tid >> 6, l = tid & 63;
  const int g = l >> 4, h = l & 15;
  const int m0 = blockIdx.x * 64;       // 32 blocks/batch; tiles never span batches
  const int b = m0 >> 11;

  // B fragment base: nt-panels 1KB apart, K-steps 8KB apart
  const short* bbase = Bpk + (size_t)(w * 256 + l) * 8;

  // 2-deep B prefetch: ks=0,1
  s16x8 bcur[4], bn1[4];
#pragma unroll
  for (int nt = 0; nt < 4; ++nt) bcur[nt] = *(const s16x8*)(bbase + nt * 512);
#pragma unroll
  for (int nt = 0; nt < 4; ++nt) bn1[nt] = *(const s16x8*)(bbase + 8192 + nt * 512);

  // DMA staging geometry: 1024 16B-granules per chunk; granule p=(row, c),
  // LDS linear at p*16, source column pre-swizzled: c_src = c ^ (row&15).
  const float* srcp[4];
  int ldsoff[4];
#pragma unroll
  for (int i = 0; i < 4; ++i) {
    const int p = w * 256 + i * 64 + l;
    const int row = p >> 4, c = p & 15;
    srcp[i] = key + (size_t)(m0 + row) * NKD + ((c ^ (row & 15)) << 2);
    ldsoff[i] = w * 4096 + i * 1024;    // wave-uniform (w, i only)
  }

  auto stage = [&](int bb, int ck) {
#pragma unroll
    for (int i = 0; i < 4; ++i)
      gload_lds16(srcp[i] + ck * 64, (char*)&As[bb][0] + ldsoff[i]);
  };

  // prologue: DMA chunk 0, barrier (drains vmcnt)
  stage(0, 0);
  __syncthreads();

  fx4 acc[4][4];
#pragma unroll
  for (int i = 0; i < 4; ++i)
#pragma unroll
    for (int j = 0; j < 4; ++j) acc[i][j] = fx4{0.f, 0.f, 0.f, 0.f};

  int buf = 0;
  for (int ck = 0; ck < 8; ++ck) {
    if (ck < 7) stage(buf ^ 1, ck + 1);   // issue-early: next chunk DMA
#pragma unroll
    for (int kl = 0; kl < 2; ++kl) {
      const int ks = ck * 2 + kl;
      s16x8 bn2[4];
      if (ks < 14) {
#pragma unroll
        for (int nt = 0; nt < 4; ++nt)
          bn2[nt] = *(const s16x8*)(bbase + (size_t)(ks + 2) * 8192 + nt * 512);
      }
      // A fragments: swizzled granule reads + cvt to bf16
      s16x8 af[4];
#pragma unroll
      for (int mt = 0; mt < 4; ++mt) {
        const int R = mt * 16 + h;
        const int c0 = kl * 8 + g * 2;
        const char* base = (const char*)&As[buf][0] + R * 256;
        fx4 lo = *(const fx4*)(base + (((c0    ) ^ h) << 4));
        fx4 hi = *(const fx4*)(base + (((c0 + 1) ^ h) << 4));
        u32x4 uu;
        uu[0] = cvt_pk_bf16(lo[0], lo[1]);
        uu[1] = cvt_pk_bf16(lo[2], lo[3]);
        uu[2] = cvt_pk_bf16(hi[0], hi[1]);
        uu[3] = cvt_pk_bf16(hi[2], hi[3]);
        af[mt] = *(s16x8*)&uu;
      }
#pragma unroll
      for (int mt = 0; mt < 4; ++mt)
#pragma unroll
        for (int nt = 0; nt < 4; ++nt)
          acc[mt][nt] = __builtin_amdgcn_mfma_f32_16x16x32_bf16(af[mt], bcur[nt], acc[mt][nt], 0, 0, 0);
#pragma unroll
      for (int nt = 0; nt < 4; ++nt) bcur[nt] = bn1[nt];
      if (ks < 14) {
#pragma unroll
        for (int nt = 0; nt < 4; ++nt) bn1[nt] = bn2[nt];
      }
    }
    __syncthreads();                      // drains this chunk's DMA; buf swap safe
    buf ^= 1;
  }

  // epilogue: score row m = m0 + mt*16 + 4g + reg  (C layout col=h, row=4g+reg)
  float qv[4], wv[4];
#pragma unroll
  for (int nt = 0; nt < 4; ++nt) {
    const int n = w * 64 + nt * 16 + h;
    qv[nt] = qpk[b * NAD + n];
    wv[nt] = Wo[n];
  }
#pragma unroll
  for (int mt = 0; mt < 4; ++mt) {
#pragma unroll
    for (int rr = 0; rr < 4; ++rr) {
      float s = fast_tanh(acc[mt][0][rr] + qv[0]) * wv[0]
              + fast_tanh(acc[mt][1][rr] + qv[1]) * wv[1]
              + fast_tanh(acc[mt][2][rr] + qv[2]) * wv[2]
              + fast_tanh(acc[mt][3][rr] + qv[3]) * wv[3];
#pragma unroll
      for (int off = 1; off < 16; off <<= 1) s += __shfl_xor(s, off, 64);
      if (h == 0) sred[w][mt * 16 + g * 4 + rr] = s;
    }
  }
  __syncthreads();
  if (tid < 64)
    score[m0 + tid] = sred[0][tid] + sred[1][tid] + sred[2][tid] + sred[3][tid];
}

// ---- kernel 3: softmax over T per batch (bo dropped: softmax shift-invariant)
__global__ void softmax_kernel(const float* __restrict__ score, float* __restrict__ attn) {
  __shared__ float redm[4];
  __shared__ float reds[4];
  const int b = blockIdx.x, tid = threadIdx.x;
  const float* s = score + (size_t)b * NT;
  float v[8];
  float m = -3.0e38f;
#pragma unroll
  for (int j = 0; j < 8; ++j) { v[j] = s[tid + j * 256]; m = fmaxf(m, v[j]); }
#pragma unroll
  for (int off = 1; off < 64; off <<= 1) m = fmaxf(m, __shfl_xor(m, off, 64));
  if ((tid & 63) == 0) redm[tid >> 6] = m;
  __syncthreads();
  m = fmaxf(fmaxf(redm[0], redm[1]), fmaxf(redm[2], redm[3]));
  float sum = 0.f;
#pragma unroll
  for (int j = 0; j < 8; ++j) { v[j] = __expf(v[j] - m); sum += v[j]; }
#pragma unroll
  for (int off = 1; off < 64; off <<= 1) sum += __shfl_xor(sum, off, 64);
  if ((tid & 63) == 0) reds[tid >> 6] = sum;
  __syncthreads();
  sum = reds[0] + reds[1] + reds[2] + reds[3];
  const float inv = 1.0f / sum;
#pragma unroll
  for (int j = 0; j < 8; ++j) attn[(size_t)b * NT + tid + j * 256] = v[j] * inv;
}

// ---- kernel 4: partial context over 64-row t-chunks (float4 loads)
__global__ void ctx_partial_kernel(const float* __restrict__ attn, const float* __restrict__ value,
                                   float* __restrict__ partial) {
  __shared__ float a[64];
  __shared__ fx4 red[128];
  const int blk = blockIdx.x;       // b*32 + tc
  const int b = blk >> 5, tc = blk & 31;
  const int tid = threadIdx.x;
  if (tid < 64) a[tid] = attn[(size_t)b * NT + tc * 64 + tid];
  __syncthreads();
  const int half = tid >> 7;        // 0: even rows, 1: odd rows
  const int vi = (tid & 127) * 4;   // 128 threads cover VD=512
  const float* vp = value + ((size_t)b * NT + tc * 64 + half) * NVD + vi;
  fx4 s = fx4{0.f, 0.f, 0.f, 0.f};
#pragma unroll 8
  for (int t = 0; t < 64; t += 2) {
    fx4 x = *(const fx4*)(vp + (size_t)t * NVD);
    const float wt = a[t + half];
    s += x * wt;
  }
  if (half) red[tid & 127] = s;
  __syncthreads();
  if (!half) {
    s += red[tid];
    *(fx4*)(partial + (size_t)blk * NVD + vi) = s;
  }
}

// ---- kernel 5: reduce partials -> context
__global__ void ctx_reduce_kernel(const float* __restrict__ partial, float* __restrict__ ctx) {
  const int i = blockIdx.x * 256 + threadIdx.x;  // < NB*NVD
  const int b = i >> 9, v = i & (NVD - 1);
  float s = 0.f;
#pragma unroll
  for (int tc = 0; tc < 32; ++tc) s += partial[(size_t)(b * 32 + tc) * NVD + v];
  ctx[i] = s;
}

extern "C" void kernel_launch(void* const* d_in, const int* in_sizes, int n_in,
                              void* d_out, int out_size, void* d_ws, size_t ws_size,
                              hipStream_t stream) {
  const float* query = (const float*)d_in[0];
  const float* key   = (const float*)d_in[1];
  const float* value = (const float*)d_in[2];
  const float* Wq    = (const float*)d_in[3];
  const float* bq    = (const float*)d_in[4];
  const float* Wk    = (const float*)d_in[5];
  const float* bk    = (const float*)d_in[6];
  const float* Wo    = (const float*)d_in[7];
  // d_in[8] = bo: unused — softmax over T is invariant to a uniform shift.

  float* out  = (float*)d_out;
  float* ctx  = out;                // [B][VD]
  float* attn = out + NB * NVD;     // [B][T]

  char* ws = (char*)d_ws;
  float* qpk     = (float*)(ws);                                   // 64 KB
  short* Bpk     = (short*)(ws + 64 * 1024);                       // 256 KB
  float* score   = (float*)(ws + (64 + 256) * 1024);               // 512 KB
  float* partial = (float*)(ws + (64 + 256 + 512) * 1024);         // 4 MB

  prep_kernel<<<NB + 16, 256, 0, stream>>>(query, Wq, bq, bk, Wk, qpk, Bpk);
  score_kernel<<<(NB * NT) / 64, 256, 0, stream>>>(key, Bpk, qpk, Wo, score);
  softmax_kernel<<<NB, 256, 0, stream>>>(score, attn);
  ctx_partial_kernel<<<NB * 32, 256, 0, stream>>>(attn, value, partial);
  ctx_reduce_kernel<<<(NB * NVD) / 256, 256, 0, stream>>>(partial, ctx);
}

// Round 10
// 155.106 us; speedup vs baseline: 1.6632x; 1.0090x over previous
//
#include <hip/hip_runtime.h>

#define NB 64
#define NT 2048
#define NQD 512
#define NKD 512
#define NVD 512
#define NAD 256

typedef __attribute__((ext_vector_type(8))) short s16x8;
typedef __attribute__((ext_vector_type(4))) float fx4;
typedef __attribute__((ext_vector_type(4))) unsigned int u32x4;

__device__ __forceinline__ short f2bf(float x) {
  union { float f; unsigned u; } v; v.f = x;
  return (short)((v.u + 0x7fffu + ((v.u >> 16) & 1u)) >> 16);  // RNE
}

__device__ __forceinline__ unsigned cvt_pk_bf16(float lo, float hi) {
  unsigned r;
  asm("v_cvt_pk_bf16_f32 %0, %1, %2" : "=v"(r) : "v"(lo), "v"(hi));
  return r;
}

// tanh(x) = 1 - 2/(1+e^{2x});  exact saturation at +/-1, rel err ~1e-7
__device__ __forceinline__ float fast_tanh(float x) {
  float e = __expf(x + x);
  return 1.0f - 2.0f * __builtin_amdgcn_rcpf(e + 1.0f);
}

__device__ __forceinline__ void gload_lds16(const void* g, void* l) {
  __builtin_amdgcn_global_load_lds(
      (const __attribute__((address_space(1))) unsigned int*)g,
      (__attribute__((address_space(3))) unsigned int*)l, 16, 0, 0);
}

// ---- kernel 1: fused prep.
// blocks 0..63:  qpk[b][n] = query[b]·Wq[:,n] + bq[n] + bk[n]
// blocks 64..79: Bpk = Wk as bf16 packed in MFMA B-fragment lane order:
//   Bpk[(ks*1024 + wnt*64 + g*16 + h)*8 + j] = bf16(Wk[ks*32+g*8+j][wnt*16+h])
__global__ void prep_kernel(const float* __restrict__ query, const float* __restrict__ Wq,
                            const float* __restrict__ bq, const float* __restrict__ bk,
                            const float* __restrict__ Wk,
                            float* __restrict__ qpk, short* __restrict__ Bpk) {
  __shared__ float q[NQD];
  const int tid = threadIdx.x;
  if (blockIdx.x < NB) {
    const int b = blockIdx.x;
    for (int k = tid; k < NQD; k += 256) q[k] = query[b * NQD + k];
    __syncthreads();
    float acc = bq[tid] + bk[tid];
#pragma unroll 8
    for (int k = 0; k < NQD; ++k) acc += q[k] * Wq[k * NAD + tid];
    qpk[b * NAD + tid] = acc;
  } else {
    const int ks = blockIdx.x - NB;          // 0..15 (K-step)
#pragma unroll
    for (int rep = 0; rep < 4; ++rep) {
      const int o = rep * 256 + tid;         // chunk id within ks: 0..1023
      const int wnt = o >> 6;
      const int l = o & 63;
      const int g = l >> 4, h = l & 15;
      const int n = wnt * 16 + h;
      const int k0 = ks * 32 + g * 8;
      s16x8 v;
#pragma unroll
      for (int j = 0; j < 8; ++j) v[j] = f2bf(Wk[(size_t)(k0 + j) * NAD + n]);
      *(s16x8*)(Bpk + (size_t)(ks * 1024 + o) * 8) = v;
    }
  }
}

// ---- kernel 2: fused GEMM(key@Wk) + tanh + ·Wo reduce -> score[b*T+t]
// BM=64, BK=64-f32 chunks (8), A staged via global_load_lds DMA into 2x16KB
// dbuf with COUNTED vmcnt waits (never drain to 0 mid-loop): chunk ck+1's
// DMA stays in flight across the barrier while chunk ck computes.
// Source-address granule swizzle (c ^= row&15), linear LDS dest, swizzled
// reads. f32->bf16 cvt at fragment-read time. B frags from Bpk (coalesced
// 1KB wave loads, L2-resident), reg-prefetched 2 K-steps deep.
__global__ void __launch_bounds__(256, 3)
score_kernel(const float* __restrict__ key, const short* __restrict__ Bpk,
             const float* __restrict__ qpk, const float* __restrict__ Wo,
             float* __restrict__ score) {
  __shared__ float As[2][64 * 64];      // 2 x 16 KB f32, granule-swizzled content
  __shared__ float sred[4][64];
  const int tid = threadIdx.x;
  const int w = tid >> 6, l = tid & 63;
  const int g = l >> 4, h = l & 15;
  const int m0 = blockIdx.x * 64;       // 32 blocks/batch; tiles never span batches
  const int b = m0 >> 11;

  // B fragment base: nt-panels 1KB apart, K-steps 8KB apart
  const short* bbase = Bpk + (size_t)(w * 256 + l) * 8;

  // 2-deep B prefetch: ks=0,1
  s16x8 bcur[4], bn1[4];
#pragma unroll
  for (int nt = 0; nt < 4; ++nt) bcur[nt] = *(const s16x8*)(bbase + nt * 512);
#pragma unroll
  for (int nt = 0; nt < 4; ++nt) bn1[nt] = *(const s16x8*)(bbase + 8192 + nt * 512);

  // DMA staging geometry: 1024 16B-granules per chunk; granule p=(row, c),
  // LDS linear at p*16, source column pre-swizzled: c_src = c ^ (row&15).
  const float* srcp[4];
  int ldsoff[4];
#pragma unroll
  for (int i = 0; i < 4; ++i) {
    const int p = w * 256 + i * 64 + l;
    const int row = p >> 4, c = p & 15;
    srcp[i] = key + (size_t)(m0 + row) * NKD + ((c ^ (row & 15)) << 2);
    ldsoff[i] = w * 4096 + i * 1024;    // wave-uniform (w, i only)
  }

  auto stage = [&](int bb, int ck) {
#pragma unroll
    for (int i = 0; i < 4; ++i)
      gload_lds16(srcp[i] + ck * 64, (char*)&As[bb][0] + ldsoff[i]);
  };

  // prologue: DMA chunks 0 and 1 (8 loads/wave in flight)
  stage(0, 0);
  stage(1, 1);

  fx4 acc[4][4];
#pragma unroll
  for (int i = 0; i < 4; ++i)
#pragma unroll
    for (int j = 0; j < 4; ++j) acc[i][j] = fx4{0.f, 0.f, 0.f, 0.f};

  for (int ck = 0; ck < 8; ++ck) {
    const int buf = ck & 1;
    // wait for chunk ck's 4 DMAs (oldest); chunk ck+1's 4 (newest) stay in
    // flight. B loads are always issued AFTER these waits and consumed
    // before the next one, so the 4 newest ops here are always DMAs.
    if (ck < 7) asm volatile("s_waitcnt vmcnt(4)" ::: "memory");
    else        asm volatile("s_waitcnt vmcnt(0)" ::: "memory");
    __builtin_amdgcn_sched_barrier(0);
    __builtin_amdgcn_s_barrier();       // all waves' chunk-ck writes visible

#pragma unroll
    for (int kl = 0; kl < 2; ++kl) {
      const int ks = ck * 2 + kl;
      s16x8 bn2[4];
      if (ks < 14) {
#pragma unroll
        for (int nt = 0; nt < 4; ++nt)
          bn2[nt] = *(const s16x8*)(bbase + (size_t)(ks + 2) * 8192 + nt * 512);
      }
      // A fragments: swizzled granule reads + cvt to bf16
      s16x8 af[4];
#pragma unroll
      for (int mt = 0; mt < 4; ++mt) {
        const int R = mt * 16 + h;
        const int c0 = kl * 8 + g * 2;
        const char* base = (const char*)&As[buf][0] + R * 256;
        fx4 lo = *(const fx4*)(base + (((c0    ) ^ h) << 4));
        fx4 hi = *(const fx4*)(base + (((c0 + 1) ^ h) << 4));
        u32x4 uu;
        uu[0] = cvt_pk_bf16(lo[0], lo[1]);
        uu[1] = cvt_pk_bf16(lo[2], lo[3]);
        uu[2] = cvt_pk_bf16(hi[0], hi[1]);
        uu[3] = cvt_pk_bf16(hi[2], hi[3]);
        af[mt] = *(s16x8*)&uu;
      }
#pragma unroll
      for (int mt = 0; mt < 4; ++mt)
#pragma unroll
        for (int nt = 0; nt < 4; ++nt)
          acc[mt][nt] = __builtin_amdgcn_mfma_f32_16x16x32_bf16(af[mt], bcur[nt], acc[mt][nt], 0, 0, 0);
#pragma unroll
      for (int nt = 0; nt < 4; ++nt) bcur[nt] = bn1[nt];
      if (ks < 14) {
#pragma unroll
        for (int nt = 0; nt < 4; ++nt) bn1[nt] = bn2[nt];
      }
    }

    __builtin_amdgcn_s_barrier();       // all waves done reading As[buf]
    if (ck < 6) stage(buf, ck + 2);     // refill freed buffer, stay 2 ahead
  }

  // epilogue: score row m = m0 + mt*16 + 4g + reg  (C layout col=h, row=4g+reg)
  float qv[4], wv[4];
#pragma unroll
  for (int nt = 0; nt < 4; ++nt) {
    const int n = w * 64 + nt * 16 + h;
    qv[nt] = qpk[b * NAD + n];
    wv[nt] = Wo[n];
  }
#pragma unroll
  for (int mt = 0; mt < 4; ++mt) {
#pragma unroll
    for (int rr = 0; rr < 4; ++rr) {
      float s = fast_tanh(acc[mt][0][rr] + qv[0]) * wv[0]
              + fast_tanh(acc[mt][1][rr] + qv[1]) * wv[1]
              + fast_tanh(acc[mt][2][rr] + qv[2]) * wv[2]
              + fast_tanh(acc[mt][3][rr] + qv[3]) * wv[3];
#pragma unroll
      for (int off = 1; off < 16; off <<= 1) s += __shfl_xor(s, off, 64);
      if (h == 0) sred[w][mt * 16 + g * 4 + rr] = s;
    }
  }
  __syncthreads();
  if (tid < 64)
    score[m0 + tid] = sred[0][tid] + sred[1][tid] + sred[2][tid] + sred[3][tid];
}

// ---- kernel 3: softmax over T per batch (bo dropped: softmax shift-invariant)
__global__ void softmax_kernel(const float* __restrict__ score, float* __restrict__ attn) {
  __shared__ float redm[4];
  __shared__ float reds[4];
  const int b = blockIdx.x, tid = threadIdx.x;
  const float* s = score + (size_t)b * NT;
  float v[8];
  float m = -3.0e38f;
#pragma unroll
  for (int j = 0; j < 8; ++j) { v[j] = s[tid + j * 256]; m = fmaxf(m, v[j]); }
#pragma unroll
  for (int off = 1; off < 64; off <<= 1) m = fmaxf(m, __shfl_xor(m, off, 64));
  if ((tid & 63) == 0) redm[tid >> 6] = m;
  __syncthreads();
  m = fmaxf(fmaxf(redm[0], redm[1]), fmaxf(redm[2], redm[3]));
  float sum = 0.f;
#pragma unroll
  for (int j = 0; j < 8; ++j) { v[j] = __expf(v[j] - m); sum += v[j]; }
#pragma unroll
  for (int off = 1; off < 64; off <<= 1) sum += __shfl_xor(sum, off, 64);
  if ((tid & 63) == 0) reds[tid >> 6] = sum;
  __syncthreads();
  sum = reds[0] + reds[1] + reds[2] + reds[3];
  const float inv = 1.0f / sum;
#pragma unroll
  for (int j = 0; j < 8; ++j) attn[(size_t)b * NT + tid + j * 256] = v[j] * inv;
}

// ---- kernel 4: partial context over 64-row t-chunks (float4 loads)
__global__ void ctx_partial_kernel(const float* __restrict__ attn, const float* __restrict__ value,
                                   float* __restrict__ partial) {
  __shared__ float a[64];
  __shared__ fx4 red[128];
  const int blk = blockIdx.x;       // b*32 + tc
  const int b = blk >> 5, tc = blk & 31;
  const int tid = threadIdx.x;
  if (tid < 64) a[tid] = attn[(size_t)b * NT + tc * 64 + tid];
  __syncthreads();
  const int half = tid >> 7;        // 0: even rows, 1: odd rows
  const int vi = (tid & 127) * 4;   // 128 threads cover VD=512
  const float* vp = value + ((size_t)b * NT + tc * 64 + half) * NVD + vi;
  fx4 s = fx4{0.f, 0.f, 0.f, 0.f};
#pragma unroll 8
  for (int t = 0; t < 64; t += 2) {
    fx4 x = *(const fx4*)(vp + (size_t)t * NVD);
    const float wt = a[t + half];
    s += x * wt;
  }
  if (half) red[tid & 127] = s;
  __syncthreads();
  if (!half) {
    s += red[tid];
    *(fx4*)(partial + (size_t)blk * NVD + vi) = s;
  }
}

// ---- kernel 5: reduce partials -> context
__global__ void ctx_reduce_kernel(const float* __restrict__ partial, float* __restrict__ ctx) {
  const int i = blockIdx.x * 256 + threadIdx.x;  // < NB*NVD
  const int b = i >> 9, v = i & (NVD - 1);
  float s = 0.f;
#pragma unroll
  for (int tc = 0; tc < 32; ++tc) s += partial[(size_t)(b * 32 + tc) * NVD + v];
  ctx[i] = s;
}

extern "C" void kernel_launch(void* const* d_in, const int* in_sizes, int n_in,
                              void* d_out, int out_size, void* d_ws, size_t ws_size,
                              hipStream_t stream) {
  const float* query = (const float*)d_in[0];
  const float* key   = (const float*)d_in[1];
  const float* value = (const float*)d_in[2];
  const float* Wq    = (const float*)d_in[3];
  const float* bq    = (const float*)d_in[4];
  const float* Wk    = (const float*)d_in[5];
  const float* bk    = (const float*)d_in[6];
  const float* Wo    = (const float*)d_in[7];
  // d_in[8] = bo: unused — softmax over T is invariant to a uniform shift.

  float* out  = (float*)d_out;
  float* ctx  = out;                // [B][VD]
  float* attn = out + NB * NVD;     // [B][T]

  char* ws = (char*)d_ws;
  float* qpk     = (float*)(ws);                                   // 64 KB
  short* Bpk     = (short*)(ws + 64 * 1024);                       // 256 KB
  float* score   = (float*)(ws + (64 + 256) * 1024);               // 512 KB
  float* partial = (float*)(ws + (64 + 256 + 512) * 1024);         // 4 MB

  prep_kernel<<<NB + 16, 256, 0, stream>>>(query, Wq, bq, bk, Wk, qpk, Bpk);
  score_kernel<<<(NB * NT) / 64, 256, 0, stream>>>(key, Bpk, qpk, Wo, score);
  softmax_kernel<<<NB, 256, 0, stream>>>(score, attn);
  ctx_partial_kernel<<<NB * 32, 256, 0, stream>>>(attn, value, partial);
  ctx_reduce_kernel<<<(NB * NVD) / 256, 256, 0, stream>>>(partial, ctx);
}